// Round 8
// baseline (177.240 us; speedup 1.0000x reference)
//
#include <hip/hip_runtime.h>

#define N 512
#define D 512
#define TILE 32        // pair tile per block: 32x32
#define P4 33          // LDS pitch in float4 (132 floats; ==4 mod 8 -> octet reads conflict-free)
#define NT 16          // N/TILE
#define NTILES 136     // upper-triangular tiles
#define NSLICE 4       // d-slices of 128 (4 warps x 32 dims each)
#define REPS 6         // DIAGNOSTIC: repeat identical work to surface pair in rocprof top-5

__device__ __forceinline__ void sl1(float& acc, float x, float y) {
    // 2*SmoothL1(d) = m*(2|d|-m), m=min(|d|,1); 0.5 applied in epilogue.
    float d  = x - y;
    float ad = fabsf(d);
    float m  = fminf(ad, 1.0f);
    acc = fmaf(m, fmaf(2.0f, ad, -m), acc);
}

__global__ __launch_bounds__(256, 4) void pair_sums_kernel(
    const float* __restrict__ Tm, const float* __restrict__ Sm,
    float* __restrict__ Pp, float* __restrict__ sums)
{
    const int mat = blockIdx.z;
    const int sl  = blockIdx.y;
    const float* __restrict__ X = mat ? Sm : Tm;
    float* __restrict__ Pm = Pp + (size_t)(mat * NSLICE + sl) * (N * N);

    // triangular tile decode -> (ti, tj), ti <= tj
    int rem = blockIdx.x, ti = 0;
    while (rem >= NT - ti) { rem -= NT - ti; ++ti; }
    const int tj = ti + rem;
    const int i0 = ti * TILE, j0 = tj * TILE, d0 = sl * (4 * TILE);

    __shared__ float4 Xi4[TILE * P4];
    __shared__ float4 Xj4[TILE * P4];

    const int t  = threadIdx.x;
    const int w  = t >> 6;        // warp id = private d-window of 32 dims
    const int l  = t & 63;
    const int rg = l >> 3;        // 0..7
    const int cg = l & 7;         // 0..7

    for (int rep = 0; rep < REPS; ++rep) {
        // stage 32 rows x 128 floats per array (1024 float4 each, 4 per thread)
        #pragma unroll
        for (int kk = 0; kk < 4; ++kk) {
            int idx = t + kk * 256;
            int row = idx >> 5;              // 32 float4 per row
            int c4  = idx & 31;
            Xi4[row * P4 + c4] = *(const float4*)&X[(size_t)(i0 + row) * D + d0 + c4 * 4];
            Xj4[row * P4 + c4] = *(const float4*)&X[(size_t)(j0 + row) * D + d0 + c4 * 4];
        }
        __syncthreads();

        // each lane: rows {rg+8m} x cols {cg+8n}, warp's 32 dims = 8 float4 steps
        float acc[4][4] = {};
        #pragma unroll 2
        for (int d4 = 0; d4 < 8; ++d4) {
            const int c = w * 8 + d4;
            float4 p[4], q[4];
            #pragma unroll
            for (int m = 0; m < 4; ++m) p[m] = Xi4[(rg + 8 * m) * P4 + c];
            #pragma unroll
            for (int n = 0; n < 4; ++n) q[n] = Xj4[(cg + 8 * n) * P4 + c];
            #pragma unroll
            for (int m = 0; m < 4; ++m)
                #pragma unroll
                for (int n = 0; n < 4; ++n) {
                    sl1(acc[m][n], p[m].x, q[n].x);
                    sl1(acc[m][n], p[m].y, q[n].y);
                    sl1(acc[m][n], p[m].z, q[n].z);
                    sl1(acc[m][n], p[m].w, q[n].w);
                }
        }

        // cross-warp reduction of the 4 d-window partials (zone reuses Xi4)
        __syncthreads();   // all compute reads done before zone clobbers Xi4
        float* zone = (float*)Xi4;
        if (w) {
            const int base = ((w - 1) * 64 + l) * 17;
            #pragma unroll
            for (int m = 0; m < 4; ++m)
                #pragma unroll
                for (int n = 0; n < 4; ++n) zone[base + m * 4 + n] = acc[m][n];
        }
        __syncthreads();

        if (w == 0) {
            #pragma unroll
            for (int ww = 0; ww < 3; ++ww) {
                const int base = (ww * 64 + l) * 17;
                #pragma unroll
                for (int m = 0; m < 4; ++m)
                    #pragma unroll
                    for (int n = 0; n < 4; ++n) acc[m][n] += zone[base + m * 4 + n];
            }
            const bool diag = (ti == tj);
            float bs = 0.f;
            #pragma unroll
            for (int m = 0; m < 4; ++m)
                #pragma unroll
                for (int n = 0; n < 4; ++n) {
                    const int li = rg + 8 * m, lj = cg + 8 * n;
                    const float s = 0.5f * acc[m][n];
                    Pm[(i0 + li) * N + (j0 + lj)] = s;    // idempotent across reps
                    if (!diag || (li <= lj)) bs += s;
                }
            #pragma unroll
            for (int off = 32; off > 0; off >>= 1) bs += __shfl_down(bs, off, 64);
            if (l == 0 && rep == 0) atomicAdd(&sums[mat], bs);  // once per call
        }
        __syncthreads();   // zone reads done before next rep restages Xi4
    }
}

__global__ __launch_bounds__(256) void final_kernel(
    const float* __restrict__ Pp, float* __restrict__ sums, float* __restrict__ out)
{
    float* fin = sums + 2;
    unsigned int* cnt = (unsigned int*)(sums + 3);

    const float NN = (float)N * (float)N;
    const float cT = NN / (2.0f * sums[0]);   // 1/mean (full mean = 2*Sum_{i<j}/N^2)
    const float cS = NN / (2.0f * sums[1]);

    const int v  = blockIdx.x * 256 + threadIdx.x;   // 65536 threads = N*N/4 float4s
    const int i  = v >> 7;
    const int jb = (v & 127) * 4;

    float local = 0.0f;
    if (jb + 3 >= i) {                // skip float4s fully below the diagonal
        float4 tq = make_float4(0.f, 0.f, 0.f, 0.f);
        float4 sq = make_float4(0.f, 0.f, 0.f, 0.f);
        #pragma unroll
        for (int s = 0; s < NSLICE; ++s) {
            float4 a = ((const float4*)(Pp + (size_t)s * (N * N)))[v];
            float4 b = ((const float4*)(Pp + (size_t)(NSLICE + s) * (N * N)))[v];
            tq.x += a.x; tq.y += a.y; tq.z += a.z; tq.w += a.w;
            sq.x += b.x; sq.y += b.y; sq.z += b.z; sq.w += b.w;
        }
        if (jb + 0 >= i) local += fabsf(tq.x * cT - sq.x * cS);
        if (jb + 1 >= i) local += fabsf(tq.y * cT - sq.y * cS);
        if (jb + 2 >= i) local += fabsf(tq.z * cT - sq.z * cS);
        if (jb + 3 >= i) local += fabsf(tq.w * cT - sq.w * cS);
    }

    #pragma unroll
    for (int off = 32; off > 0; off >>= 1) local += __shfl_down(local, off, 64);
    __shared__ float wpart[4];
    if ((threadIdx.x & 63) == 0) wpart[threadIdx.x >> 6] = local;
    __syncthreads();

    if (threadIdx.x == 0) {
        atomicAdd(fin, wpart[0] + wpart[1] + wpart[2] + wpart[3]);
        __threadfence();
        unsigned int old = atomicAdd(cnt, 1u);
        if (old == gridDim.x - 1) {
            float tot = atomicAdd(fin, 0.0f);
            out[0] = 2.0f * tot;
        }
    }
}

extern "C" void kernel_launch(void* const* d_in, const int* in_sizes, int n_in,
                              void* d_out, int out_size, void* d_ws, size_t ws_size,
                              hipStream_t stream) {
    const float* teacher = (const float*)d_in[0];
    const float* student = (const float*)d_in[1];
    float* out  = (float*)d_out;
    float* Pp   = (float*)d_ws;                         // [2][NSLICE][N*N] = 8 MB
    float* sums = Pp + (size_t)2 * NSLICE * N * N;      // sums[2], fin, cnt

    hipMemsetAsync(sums, 0, 4 * sizeof(float), stream);

    dim3 grid(NTILES, NSLICE, 2);
    pair_sums_kernel<<<grid, 256, 0, stream>>>(teacher, student, Pp, sums);
    final_kernel<<<N * N / 4 / 256, 256, 0, stream>>>(Pp, sums, out);
}

// Round 10
// 86.270 us; speedup vs baseline: 2.0545x; 2.0545x over previous
//
#include <hip/hip_runtime.h>

#define N 512
#define D 512
#define TILE 32        // pair tile per block: 32x32
#define NT 16          // N/TILE
#define NTILES 136     // upper-triangular tiles
#define NSLICE 4       // d-slices of 128 (4 warps x 32 dims each); slab 8 MB

__device__ __forceinline__ void sl1(float& acc, float x, float y) {
    // 2*SmoothL1(d) = m*(2|d|-m), m=min(|d|,1); 0.5 applied in epilogue.
    float d  = x - y;
    float ad = fabsf(d);
    float m  = fminf(ad, 1.0f);
    acc = fmaf(m, fmaf(2.0f, ad, -m), acc);
}

// LDS: pitch exactly 32 float4 per row, XOR-swizzled columns (c ^ (row&7)).
// -> 2 x 16 KB = 32 KB exactly -> 5 blocks/CU (capacity 1280 >= grid 1088):
//    every block resident from t=0, no tail round (R8: tail was ~50% of time).
// Bank math (compute reads): rows {rg+8m} at warp-uniform c -> addresses
// (rg+8m)*32 + (c^rg); bank = ((c^rg)&7)*4 -> 8 octet-broadcast addresses
// covering all 32 banks. Conflict-free without padding.

__global__ __launch_bounds__(256, 5) void pair_sums_kernel(
    const float* __restrict__ Tm, const float* __restrict__ Sm,
    float* __restrict__ Pp, float* __restrict__ sums)
{
    const int mat = blockIdx.z;
    const int sl  = blockIdx.y;
    const float* __restrict__ X = mat ? Sm : Tm;
    float* __restrict__ Pm = Pp + (size_t)(mat * NSLICE + sl) * (N * N);

    // triangular tile decode -> (ti, tj), ti <= tj
    int rem = blockIdx.x, ti = 0;
    while (rem >= NT - ti) { rem -= NT - ti; ++ti; }
    const int tj = ti + rem;
    const int i0 = ti * TILE, j0 = tj * TILE, d0 = sl * (4 * TILE);

    __shared__ float4 Xi4[TILE * 32];
    __shared__ float4 Xj4[TILE * 32];

    const int t  = threadIdx.x;
    const int w  = t >> 6;        // warp id = private d-window of 32 dims
    const int l  = t & 63;
    const int rg = l >> 3;        // 0..7
    const int cg = l & 7;         // 0..7

    // stage 32 rows x 128 floats per array (1024 float4 each, 4 per thread)
    #pragma unroll
    for (int kk = 0; kk < 4; ++kk) {
        int idx = t + kk * 256;
        int row = idx >> 5;              // 32 float4 per row
        int c4  = idx & 31;
        int sc  = c4 ^ (row & 7);        // XOR swizzle
        Xi4[row * 32 + sc] = *(const float4*)&X[(size_t)(i0 + row) * D + d0 + c4 * 4];
        Xj4[row * 32 + sc] = *(const float4*)&X[(size_t)(j0 + row) * D + d0 + c4 * 4];
    }
    __syncthreads();

    // each lane: rows {rg+8m} x cols {cg+8n}; warp's 32 dims = 8 float4 steps
    float acc[4][4] = {};
    #pragma unroll 2
    for (int d4 = 0; d4 < 8; ++d4) {
        const int c = w * 8 + d4;
        float4 p[4], q[4];
        #pragma unroll
        for (int m = 0; m < 4; ++m) p[m] = Xi4[(rg + 8 * m) * 32 + (c ^ rg)];
        #pragma unroll
        for (int n = 0; n < 4; ++n) q[n] = Xj4[(cg + 8 * n) * 32 + (c ^ cg)];
        #pragma unroll
        for (int m = 0; m < 4; ++m)
            #pragma unroll
            for (int n = 0; n < 4; ++n) {
                sl1(acc[m][n], p[m].x, q[n].x);
                sl1(acc[m][n], p[m].y, q[n].y);
                sl1(acc[m][n], p[m].z, q[n].z);
                sl1(acc[m][n], p[m].w, q[n].w);
            }
    }

    // cross-warp reduction of the 4 d-window partials (zone reuses Xi4)
    __syncthreads();   // all compute reads done before zone clobbers Xi4
    float* zone = (float*)Xi4;
    if (w) {
        const int base = ((w - 1) * 64 + l) * 17;   // stride 17: bijective mod 32
        #pragma unroll
        for (int m = 0; m < 4; ++m)
            #pragma unroll
            for (int n = 0; n < 4; ++n) zone[base + m * 4 + n] = acc[m][n];
    }
    __syncthreads();

    if (w == 0) {
        #pragma unroll
        for (int ww = 0; ww < 3; ++ww) {
            const int base = (ww * 64 + l) * 17;
            #pragma unroll
            for (int m = 0; m < 4; ++m)
                #pragma unroll
                for (int n = 0; n < 4; ++n) acc[m][n] += zone[base + m * 4 + n];
        }
        const bool diag = (ti == tj);
        float bs = 0.f;
        #pragma unroll
        for (int m = 0; m < 4; ++m)
            #pragma unroll
            for (int n = 0; n < 4; ++n) {
                const int li = rg + 8 * m, lj = cg + 8 * n;
                const float s = 0.5f * acc[m][n];
                Pm[(i0 + li) * N + (j0 + lj)] = s;    // full tile; holes masked in final
                if (!diag || (li <= lj)) bs += s;     // count each upper pair once
            }
        #pragma unroll
        for (int off = 32; off > 0; off >>= 1) bs += __shfl_down(bs, off, 64);
        if (l == 0) atomicAdd(&sums[mat], bs);
    }
}

__global__ __launch_bounds__(256) void final_kernel(
    const float* __restrict__ Pp, float* __restrict__ sums, float* __restrict__ out)
{
    float* fin = sums + 2;
    unsigned int* cnt = (unsigned int*)(sums + 3);

    const float NN = (float)N * (float)N;
    const float cT = NN / (2.0f * sums[0]);   // 1/mean (full mean = 2*Sum_{i<j}/N^2)
    const float cS = NN / (2.0f * sums[1]);

    const int v  = blockIdx.x * 256 + threadIdx.x;   // 65536 threads = N*N/4 float4s
    const int i  = v >> 7;
    const int jb = (v & 127) * 4;

    float local = 0.0f;
    if (jb + 3 >= i) {                // skip float4s fully below the diagonal
        float4 tq = make_float4(0.f, 0.f, 0.f, 0.f);
        float4 sq = make_float4(0.f, 0.f, 0.f, 0.f);
        #pragma unroll
        for (int s = 0; s < NSLICE; ++s) {
            float4 a = ((const float4*)(Pp + (size_t)s * (N * N)))[v];
            float4 b = ((const float4*)(Pp + (size_t)(NSLICE + s) * (N * N)))[v];
            tq.x += a.x; tq.y += a.y; tq.z += a.z; tq.w += a.w;
            sq.x += b.x; sq.y += b.y; sq.z += b.z; sq.w += b.w;
        }
        // exact per-element mask excludes unwritten (poisoned) below-diagonal slots
        if (jb + 0 >= i) local += fabsf(tq.x * cT - sq.x * cS);
        if (jb + 1 >= i) local += fabsf(tq.y * cT - sq.y * cS);
        if (jb + 2 >= i) local += fabsf(tq.z * cT - sq.z * cS);
        if (jb + 3 >= i) local += fabsf(tq.w * cT - sq.w * cS);
    }

    #pragma unroll
    for (int off = 32; off > 0; off >>= 1) local += __shfl_down(local, off, 64);
    __shared__ float wpart[4];
    if ((threadIdx.x & 63) == 0) wpart[threadIdx.x >> 6] = local;
    __syncthreads();

    if (threadIdx.x == 0) {
        atomicAdd(fin, wpart[0] + wpart[1] + wpart[2] + wpart[3]);
        __threadfence();
        unsigned int old = atomicAdd(cnt, 1u);
        if (old == gridDim.x - 1) {              // last block: all adds visible
            float tot = atomicAdd(fin, 0.0f);    // atomic read of the total
            out[0] = 2.0f * tot;                 // upper-tri counted twice
        }
    }
}

extern "C" void kernel_launch(void* const* d_in, const int* in_sizes, int n_in,
                              void* d_out, int out_size, void* d_ws, size_t ws_size,
                              hipStream_t stream) {
    const float* teacher = (const float*)d_in[0];
    const float* student = (const float*)d_in[1];
    float* out  = (float*)d_out;
    float* Pp   = (float*)d_ws;                         // [2][NSLICE][N*N] = 8 MB
    float* sums = Pp + (size_t)2 * NSLICE * N * N;      // sums[2], fin, cnt

    hipMemsetAsync(sums, 0, 4 * sizeof(float), stream);

    dim3 grid(NTILES, NSLICE, 2);
    pair_sums_kernel<<<grid, 256, 0, stream>>>(teacher, student, Pp, sums);
    final_kernel<<<N * N / 4 / 256, 256, 0, stream>>>(Pp, sums, out);
}